// Round 20
// baseline (144.307 us; speedup 1.0000x reference)
//
#include <hip/hip_runtime.h>

typedef __bf16 bf16_t;
typedef __bf16 bf16x8 __attribute__((ext_vector_type(8)));
typedef __bf16 bf16x4 __attribute__((ext_vector_type(4)));
typedef __bf16 bf16x2 __attribute__((ext_vector_type(2)));
typedef float  f32x4  __attribute__((ext_vector_type(4)));

#define LOG2E 1.44269504088896340736f

// global -> LDS direct (width 16B). LDS dest is wave-uniform base + lane*16.
#define GLDS(gp, lp)                                                           \
  __builtin_amdgcn_global_load_lds(                                            \
      (const __attribute__((address_space(1))) void*)(gp),                     \
      (__attribute__((address_space(3))) void*)(lp), 16, 0, 0)

// ---------------- fused prep: 4x weight transpose + RoPE table ----------------
__global__ void prep_k(const float* __restrict__ Wq, const float* __restrict__ Wk,
                       const float* __restrict__ Wv, const float* __restrict__ Wo,
                       bf16_t* __restrict__ WqT, bf16_t* __restrict__ WkT,
                       bf16_t* __restrict__ WvT, bf16_t* __restrict__ WoT,
                       float* __restrict__ cs, float* __restrict__ sn) {
  const int bx = blockIdx.x;
  const int tx = threadIdx.x, ty = threadIdx.y;  // (32,8)
  if (bx >= 160) {  // RoPE table: i over S*32 = 65536
    const int i = ((bx - 160) * 64 + blockIdx.y) * 256 + ty * 32 + tx;
    const int s = i >> 5, j = i & 31;
    const float theta = powf(10000.0f, -(float)j * (1.0f / 32.0f));
    const float a = (float)s * theta;
    cs[i] = cosf(a);
    sn[i] = sinf(a);
    return;
  }
  __shared__ float tile[32][33];
  const float* in; bf16_t* out; int C, cbl;
  if (bx < 64)      { in = Wq; out = WqT; C = 2048; cbl = bx; }
  else if (bx < 80) { in = Wk; out = WkT; C = 512;  cbl = bx - 64; }
  else if (bx < 96) { in = Wv; out = WvT; C = 512;  cbl = bx - 80; }
  else              { in = Wo; out = WoT; C = 2048; cbl = bx - 96; }
  const int R = 2048;
  int c0 = cbl * 32, r0 = blockIdx.y * 32;
  #pragma unroll
  for (int k = 0; k < 32; k += 8)
    tile[ty + k][tx] = in[(size_t)(r0 + ty + k) * C + c0 + tx];
  __syncthreads();
  #pragma unroll
  for (int k = 0; k < 32; k += 8)
    out[(size_t)(c0 + ty + k) * R + r0 + tx] = (bf16_t)tile[tx][ty + k];
}

// ---------------- fused f32 -> bf16 cast of Q,K,V ----------------
__global__ __launch_bounds__(256) void cast3_k(const float* __restrict__ A,
                                               const float* __restrict__ B,
                                               const float* __restrict__ C,
                                               bf16_t* __restrict__ oa,
                                               bf16_t* __restrict__ ob,
                                               bf16_t* __restrict__ oc) {
  const int b = blockIdx.x;
  const float* in; bf16_t* out;
  if (b < 2048) { in = A; out = oa; }
  else if (b < 4096) { in = B; out = ob; }
  else { in = C; out = oc; }
  const int j = (b & 2047) * 256 + threadIdx.x;
  const float4 v0 = *(const float4*)&in[(size_t)j * 8];
  const float4 v1 = *(const float4*)&in[(size_t)j * 8 + 4];
  bf16x8 o;
  o[0]=(bf16_t)v0.x; o[1]=(bf16_t)v0.y; o[2]=(bf16_t)v0.z; o[3]=(bf16_t)v0.w;
  o[4]=(bf16_t)v1.x; o[5]=(bf16_t)v1.y; o[6]=(bf16_t)v1.z; o[7]=(bf16_t)v1.w;
  *(bf16x8*)&out[(size_t)j * 8] = o;
}

// XCD chunking (nb divisible by 8) + 4x4 supertile serpentine mapping
__device__ __forceinline__ int xcd_swz(int bid, int nb) {
  const int q = nb >> 3;
  return (bid & 7) * q + (bid >> 3);
}
__device__ __forceinline__ void st_map(int lin, int nstc, int& rb, int& cb) {
  const int stid = lin >> 4, w = lin & 15;
  const int sr = stid / nstc, t = stid - sr * nstc;
  const int sc = (sr & 1) ? (nstc - 1 - t) : t;
  rb = sr * 4 + (w >> 2);
  cb = sc * 4 + (w & 3);
}

// ---------------- GEMM via global_load_lds (r13 form): BK=64 ----------------
// Linear LDS rows of 64 bf16; source pre-swizzled by chunk^(row&7); reads apply
// the same XOR -> 2-way bank aliasing (free).
// MODE 0 (QKV, 768 blocks, 64x128): cb<16 Q->RoPE qh; cb<20 K->RoPE kgr; else V->vT
// MODE 1 (O-proj, 1024 blocks, 64x64): f32 out + bias
template<int MODE>
__global__ __launch_bounds__(256) void gemm_glds_k(
    const bf16_t* __restrict__ Aq, const bf16_t* __restrict__ Ak, const bf16_t* __restrict__ Av,
    const bf16_t* __restrict__ Bq, const bf16_t* __restrict__ Bk, const bf16_t* __restrict__ Bv,
    const int K, const float* __restrict__ cs, const float* __restrict__ sn,
    bf16_t* __restrict__ oq, bf16_t* __restrict__ okg, bf16_t* __restrict__ ovt,
    float* __restrict__ ofp, const float* __restrict__ bias, const int S) {
  constexpr int BN   = (MODE == 0) ? 128 : 64;   // N-tile
  constexpr int NI   = BN / 32;                  // N frags per wave
  constexpr int BU   = BN / 32;                  // B staging units per wave
  constexpr int NB   = (MODE == 0) ? 768 : 1024;
  constexpr int NSTC = (MODE == 0) ? 6 : 8;
  __shared__ bf16_t a_lds[64 * 64];
  __shared__ bf16_t b_lds[BN * 64];
  const int tid = threadIdx.x, wid = tid >> 6, lane = tid & 63;
  const int fr = lane & 15, kg = lane >> 4;

  const int lin = xcd_swz(blockIdx.x, NB);
  int rb, cb; st_map(lin, NSTC, rb, cb);
  const bf16_t* Ap; const bf16_t* Bp; int emode, col0;
  if (MODE == 1)    { Ap = Aq; Bp = Bq; emode = 3; col0 = cb * BN; }
  else if (cb < 16) { Ap = Aq; Bp = Bq; emode = 0; col0 = cb * 128; }
  else if (cb < 20) { Ap = Ak; Bp = Bk; emode = 1; col0 = (cb - 16) * 128; }
  else              { Ap = Av; Bp = Bv; emode = 2; col0 = (cb - 20) * 128; }
  const int row0 = rb * 64;
  const int wr = (wid >> 1) * 32, wc = (wid & 1) * (BN / 2);

  f32x4 acc[2][NI];
  #pragma unroll
  for (int i = 0; i < 2; ++i)
    #pragma unroll
    for (int j = 0; j < NI; ++j)
      acc[i][j] = (f32x4){0.f, 0.f, 0.f, 0.f};

  // staging: lane l -> row sub*8 + (l>>3), LDS chunk l&7; source chunk (l&7)^(row&7).
  const int rloc = lane >> 3;
  const int schunk = ((lane & 7) ^ rloc) * 8;
  const bf16_t* gA0 = Ap + (size_t)(row0 + (wid * 2 + 0) * 8 + rloc) * K + schunk;
  const bf16_t* gA1 = Ap + (size_t)(row0 + (wid * 2 + 1) * 8 + rloc) * K + schunk;
  bf16_t* lA0 = &a_lds[(wid * 2 + 0) * 512];
  bf16_t* lA1 = &a_lds[(wid * 2 + 1) * 512];
  const bf16_t* gB[BU];
  bf16_t* lB[BU];
  #pragma unroll
  for (int u = 0; u < BU; ++u) {
    gB[u] = Bp + (size_t)(col0 + (wid * BU + u) * 8 + rloc) * K + schunk;
    lB[u] = &b_lds[(wid * BU + u) * 512];
  }

  for (int kt = 0; kt < K; kt += 64) {
    __syncthreads();
    GLDS(gA0 + kt, lA0);
    GLDS(gA1 + kt, lA1);
    #pragma unroll
    for (int u = 0; u < BU; ++u) GLDS(gB[u] + kt, lB[u]);
    __syncthreads();
    #pragma unroll
    for (int ks = 0; ks < 2; ++ks) {
      bf16x8 af[2], bfr[NI];
      #pragma unroll
      for (int mi = 0; mi < 2; ++mi) {
        const int r = wr + mi * 16 + fr;
        af[mi] = *(const bf16x8*)&a_lds[r * 64 + (((ks * 4 + kg) ^ (fr & 7)) * 8)];
      }
      #pragma unroll
      for (int ni = 0; ni < NI; ++ni) {
        const int r = wc + ni * 16 + fr;
        bfr[ni] = *(const bf16x8*)&b_lds[r * 64 + (((ks * 4 + kg) ^ (fr & 7)) * 8)];
      }
      #pragma unroll
      for (int mi = 0; mi < 2; ++mi)
        #pragma unroll
        for (int ni = 0; ni < NI; ++ni)
          acc[mi][ni] = __builtin_amdgcn_mfma_f32_16x16x32_bf16(af[mi], bfr[ni], acc[mi][ni], 0, 0, 0);
    }
  }

  #pragma unroll
  for (int mi = 0; mi < 2; ++mi) {
    #pragma unroll
    for (int ni = 0; ni < NI; ++ni) {
      #pragma unroll
      for (int r = 0; r < 4; ++r) {
        const int grow = row0 + wr + mi * 16 + kg * 4 + r;  // C row = 4*(lane>>4)+reg
        const int gcol = col0 + wc + ni * 16 + fr;          // C col = lane&15
        float v = acc[mi][ni][r];
        if (emode == 3) {
          ofp[(size_t)grow * 2048 + gcol] = v + bias[gcol];
        } else if (emode == 2) {
          const int gi = gcol >> 6, d = gcol & 63;
          ovt[((size_t)gi * 64 + d) * S + grow] = (bf16_t)v;
        } else {
          const float pv = __shfl_xor(v, 1);  // RoPE partner (d^1), same row
          const int d = gcol & 63, p = d >> 1, hh = gcol >> 6;
          const float c = cs[grow * 32 + p], s = sn[grow * 32 + p];
          float o = (d & 1) ? fmaf(pv, s, v * c) : fmaf(-pv, s, v * c);
          if (emode == 0) {
            o *= 0.125f * LOG2E;  // fold 1/sqrt(64) and log2(e) into q
            oq[((size_t)hh * S + grow) * 64 + d] = (bf16_t)o;
          } else {
            okg[((size_t)hh * S + grow) * 64 + d] = (bf16_t)o;
          }
        }
      }
    }
  }
}

// XOR-swizzled LDS index (T2): row stride 64 bf16 (128B), 16B chunk c^(row&7).
__device__ __forceinline__ int swz8(int r, int c) { return r * 64 + (((c) ^ (r & 7)) << 3); }

// ---------------- flash attention v4 + T5 setprio around MFMA clusters ----------------
__global__ __launch_bounds__(256) void attn_k(
    const bf16_t* __restrict__ qh,   // [32][S][64], pre-scaled by 0.125*log2e
    const bf16_t* __restrict__ kgr,  // [8][S][64]
    const bf16_t* __restrict__ vtg,  // [8][64][S]
    const int* __restrict__ amask,   // [S]
    bf16_t* __restrict__ ao,         // [S][2048]
    const int S) {
  __shared__ bf16_t k_lds[64 * 64];
  __shared__ bf16_t vt_lds[64 * 64];
  __shared__ bf16_t p_lds[4][16 * 64];
  const int tid = threadIdx.x, wid = tid >> 6, lane = tid & 63;
  const int fr = lane & 15, kgp = lane >> 4;
  const int h = blockIdx.x, g = h >> 2;
  const int qb = 31 - blockIdx.y;      // LPT: heavy blocks first in dispatch order
  const int q0 = qb * 64 + wid * 16;
  const int qg = q0 + fr;

  const bf16_t* qbase = qh + ((size_t)h * S + q0 + fr) * 64;
  const bf16x8 qf0 = *(const bf16x8*)&qbase[kgp * 8];
  const bf16x8 qf1 = *(const bf16x8*)&qbase[32 + kgp * 8];

  f32x4 oacc[4];
  #pragma unroll
  for (int t = 0; t < 4; ++t) oacc[t] = (f32x4){0.f, 0.f, 0.f, 0.f};
  float m_ = -1e30f, l_ = 0.f;

  const int srow = tid >> 2, sc4 = tid & 3;
  const bf16_t* kbase = kgr + (size_t)g * S * 64;
  const bf16_t* vbase = vtg + (size_t)g * 64 * S;
  const int cmax = qb + 1;

  bf16x8 nk0 = *(const bf16x8*)&kbase[(size_t)srow * 64 + sc4 * 8];
  bf16x8 nk1 = *(const bf16x8*)&kbase[(size_t)srow * 64 + 32 + sc4 * 8];
  bf16x8 nv0 = *(const bf16x8*)&vbase[(size_t)srow * S + sc4 * 8];
  bf16x8 nv1 = *(const bf16x8*)&vbase[(size_t)srow * S + 32 + sc4 * 8];
  int mvc = amask[lane];
  *(bf16x8*)&k_lds[swz8(srow, sc4)]      = nk0;
  *(bf16x8*)&k_lds[swz8(srow, 4 + sc4)]  = nk1;
  *(bf16x8*)&vt_lds[swz8(srow, sc4)]     = nv0;
  *(bf16x8*)&vt_lds[swz8(srow, 4 + sc4)] = nv1;
  __syncthreads();

  for (int c = 0; c < cmax; ++c) {
    const int kc0 = c * 64;
    const unsigned long long pm = __ballot(mvc == 0);
    const bool more = (c + 1 < cmax);
    if (more) {  // issue-early prefetch (written after compute)
      const int kc1 = kc0 + 64;
      nk0 = *(const bf16x8*)&kbase[(size_t)(kc1 + srow) * 64 + sc4 * 8];
      nk1 = *(const bf16x8*)&kbase[(size_t)(kc1 + srow) * 64 + 32 + sc4 * 8];
      nv0 = *(const bf16x8*)&vbase[(size_t)srow * S + kc1 + sc4 * 8];
      nv1 = *(const bf16x8*)&vbase[(size_t)srow * S + kc1 + 32 + sc4 * 8];
      mvc = amask[kc1 + lane];
    }

    f32x4 sc[4];
    __builtin_amdgcn_s_setprio(1);   // T5: QK cluster
    #pragma unroll
    for (int a = 0; a < 4; ++a) {
      const bf16x8 ka0 = *(const bf16x8*)&k_lds[swz8(a * 16 + fr, kgp)];
      const bf16x8 ka1 = *(const bf16x8*)&k_lds[swz8(a * 16 + fr, 4 + kgp)];
      f32x4 z = (f32x4){0.f, 0.f, 0.f, 0.f};
      z = __builtin_amdgcn_mfma_f32_16x16x32_bf16(ka0, qf0, z, 0, 0, 0);
      z = __builtin_amdgcn_mfma_f32_16x16x32_bf16(ka1, qf1, z, 0, 0, 0);
      sc[a] = z;
    }
    __builtin_amdgcn_s_setprio(0);

    if (c == qb) {  // causal: only the diagonal chunk can cross
      #pragma unroll
      for (int a = 0; a < 4; ++a)
        #pragma unroll
        for (int r = 0; r < 4; ++r) {
          const int kl = a * 16 + 4 * kgp + r;
          if (kc0 + kl > qg) sc[a][r] = -1e30f;
        }
    }
    if (pm) {       // pad mask: all-ones input -> skipped (wave-uniform)
      #pragma unroll
      for (int a = 0; a < 4; ++a)
        #pragma unroll
        for (int r = 0; r < 4; ++r) {
          const int kl = a * 16 + 4 * kgp + r;
          if ((pm >> kl) & 1) sc[a][r] = -1e30f;
        }
    }

    float t0 = fmaxf(fmaxf(sc[0][0], sc[0][1]), fmaxf(sc[0][2], sc[0][3]));
    float t1 = fmaxf(fmaxf(sc[1][0], sc[1][1]), fmaxf(sc[1][2], sc[1][3]));
    float t2 = fmaxf(fmaxf(sc[2][0], sc[2][1]), fmaxf(sc[2][2], sc[2][3]));
    float t3 = fmaxf(fmaxf(sc[3][0], sc[3][1]), fmaxf(sc[3][2], sc[3][3]));
    float smax = fmaxf(fmaxf(t0, t1), fmaxf(t2, t3));
    smax = fmaxf(smax, __shfl_xor(smax, 16));
    smax = fmaxf(smax, __shfl_xor(smax, 32));

    // defer-max (T13): skip rescale while the running max grows < 8 (log2 units)
    const bool rescale = !__all(smax <= m_ + 8.0f);
    if (rescale) {
      const float mn = fmaxf(m_, smax);
      const float al = exp2f(m_ - mn);
      m_ = mn;
      #pragma unroll
      for (int t = 0; t < 4; ++t)
        #pragma unroll
        for (int r = 0; r < 4; ++r) oacc[t][r] *= al;
      l_ *= al;
    }

    float ps = 0.f;
    #pragma unroll
    for (int a = 0; a < 4; ++a)
      #pragma unroll
      for (int r = 0; r < 4; ++r) {
        const float p = exp2f(sc[a][r] - m_);
        sc[a][r] = p;
        ps += p;
      }
    ps += __shfl_xor(ps, 16);
    ps += __shfl_xor(ps, 32);
    l_ += ps;

    #pragma unroll
    for (int a = 0; a < 4; ++a) {
      bf16x4 w;
      w[0] = (bf16_t)sc[a][0];
      w[1] = (bf16_t)sc[a][1];
      w[2] = (bf16_t)sc[a][2];
      w[3] = (bf16_t)sc[a][3];
      const int off = a * 16 + 4 * kgp;
      *(bf16x4*)&p_lds[wid][fr * 64 + (((off >> 3) ^ (fr & 7)) << 3) + (off & 7)] = w;
    }
    const bf16x8 pa0 = *(const bf16x8*)&p_lds[wid][swz8(fr, kgp)];
    const bf16x8 pa1 = *(const bf16x8*)&p_lds[wid][swz8(fr, 4 + kgp)];

    __builtin_amdgcn_s_setprio(1);   // T5: PV cluster
    #pragma unroll
    for (int t = 0; t < 4; ++t) {
      const bf16x8 vb0 = *(const bf16x8*)&vt_lds[swz8(t * 16 + fr, kgp)];
      const bf16x8 vb1 = *(const bf16x8*)&vt_lds[swz8(t * 16 + fr, 4 + kgp)];
      oacc[t] = __builtin_amdgcn_mfma_f32_16x16x32_bf16(vb0, pa0, oacc[t], 0, 0, 0);
      oacc[t] = __builtin_amdgcn_mfma_f32_16x16x32_bf16(vb1, pa1, oacc[t], 0, 0, 0);
    }
    __builtin_amdgcn_s_setprio(0);

    if (more) {
      __syncthreads();
      *(bf16x8*)&k_lds[swz8(srow, sc4)]      = nk0;
      *(bf16x8*)&k_lds[swz8(srow, 4 + sc4)]  = nk1;
      *(bf16x8*)&vt_lds[swz8(srow, sc4)]     = nv0;
      *(bf16x8*)&vt_lds[swz8(srow, 4 + sc4)] = nv1;
      __syncthreads();
    }
  }

  const float inv = 1.0f / l_;
  #pragma unroll
  for (int t = 0; t < 4; ++t) {
    bf16x4 o4;
    #pragma unroll
    for (int r = 0; r < 4; ++r) o4[r] = (bf16_t)(oacc[t][r] * inv);
    *(bf16x4*)&ao[(size_t)(q0 + fr) * 2048 + h * 64 + t * 16 + 4 * kgp] = o4;
  }
}

// ---------------- launcher ----------------
extern "C" void kernel_launch(void* const* d_in, const int* in_sizes, int n_in,
                              void* d_out, int out_size, void* d_ws, size_t ws_size,
                              hipStream_t stream) {
  const float* Q  = (const float*)d_in[0];
  const float* K  = (const float*)d_in[1];
  const float* V  = (const float*)d_in[2];
  const int*   am = (const int*)d_in[3];
  const float* Wq = (const float*)d_in[4];
  const float* Wk = (const float*)d_in[5];
  const float* Wv = (const float*)d_in[6];
  const float* Wo = (const float*)d_in[7];
  const float* bo = (const float*)d_in[8];
  float* out = (float*)d_out;

  const int S = 2048, D = 2048;
  char* w = (char*)d_ws;
  const size_t MB = 1u << 20;
  bf16_t* WqT = (bf16_t*)(w + 0 * MB);   // [D][D]
  bf16_t* WoT = (bf16_t*)(w + 8 * MB);   // [D][D]
  bf16_t* WkT = (bf16_t*)(w + 16 * MB);  // [KV][D]
  bf16_t* WvT = (bf16_t*)(w + 18 * MB);
  bf16_t* qh  = (bf16_t*)(w + 20 * MB);  // [32][S][64]
  bf16_t* kgr = (bf16_t*)(w + 28 * MB);  // [8][S][64]
  bf16_t* vtg = (bf16_t*)(w + 30 * MB);  // [8][64][S]
  bf16_t* ao  = (bf16_t*)(w + 32 * MB);  // [S][D]
  bf16_t* Qb  = (bf16_t*)(w + 40 * MB);  // [S][D] bf16
  bf16_t* Kb  = (bf16_t*)(w + 48 * MB);
  bf16_t* Vb  = (bf16_t*)(w + 56 * MB);
  float*  cs  = (float*)(w + 64 * MB);   // [S][32]
  float*  sn  = (float*)(w + 64 * MB + 256 * 1024);

  // fused prep: weight transposes + RoPE table
  prep_k<<<dim3(164, 64), dim3(32, 8), 0, stream>>>(Wq, Wk, Wv, Wo, WqT, WkT, WvT, WoT, cs, sn);
  // f32 -> bf16 cast of Q,K,V (one-time 72 MB stream; pays for halved A re-reads)
  cast3_k<<<6144, 256, 0, stream>>>(Q, K, V, Qb, Kb, Vb);

  // fused Q+K+V projections: 768 blocks (64x128 tiles), all-GLDS bf16 staging
  gemm_glds_k<0><<<768, 256, 0, stream>>>(Qb, Kb, Vb, WqT, WkT, WvT, D,
                                          cs, sn, qh, kgr, vtg, nullptr, nullptr, S);

  // attention (r11 kernel + T5 setprio)
  attn_k<<<dim3(32, 32), 256, 0, stream>>>(qh, kgr, vtg, am, ao, S);

  // O-proj: 1024 blocks (64x64 tiles), global_load_lds staging
  gemm_glds_k<1><<<1024, 256, 0, stream>>>(ao, nullptr, nullptr, WoT, nullptr, nullptr,
                                           D, nullptr, nullptr, nullptr, nullptr, nullptr,
                                           out, bo, S);
}

// Round 21
// 139.078 us; speedup vs baseline: 1.0376x; 1.0376x over previous
//
#include <hip/hip_runtime.h>

typedef __bf16 bf16_t;
typedef __bf16 bf16x8 __attribute__((ext_vector_type(8)));
typedef __bf16 bf16x4 __attribute__((ext_vector_type(4)));
typedef __bf16 bf16x2 __attribute__((ext_vector_type(2)));
typedef float  f32x4  __attribute__((ext_vector_type(4)));

#define LOG2E 1.44269504088896340736f

// global -> LDS direct (width 16B). LDS dest is wave-uniform base + lane*16.
#define GLDS(gp, lp)                                                           \
  __builtin_amdgcn_global_load_lds(                                            \
      (const __attribute__((address_space(1))) void*)(gp),                     \
      (__attribute__((address_space(3))) void*)(lp), 16, 0, 0)

// ---------------- fused prep: 4x weight transpose + RoPE table ----------------
__global__ void prep_k(const float* __restrict__ Wq, const float* __restrict__ Wk,
                       const float* __restrict__ Wv, const float* __restrict__ Wo,
                       bf16_t* __restrict__ WqT, bf16_t* __restrict__ WkT,
                       bf16_t* __restrict__ WvT, bf16_t* __restrict__ WoT,
                       float* __restrict__ cs, float* __restrict__ sn) {
  const int bx = blockIdx.x;
  const int tx = threadIdx.x, ty = threadIdx.y;  // (32,8)
  if (bx >= 160) {  // RoPE table: i over S*32 = 65536
    const int i = ((bx - 160) * 64 + blockIdx.y) * 256 + ty * 32 + tx;
    const int s = i >> 5, j = i & 31;
    const float theta = powf(10000.0f, -(float)j * (1.0f / 32.0f));
    const float a = (float)s * theta;
    cs[i] = cosf(a);
    sn[i] = sinf(a);
    return;
  }
  __shared__ float tile[32][33];
  const float* in; bf16_t* out; int C, cbl;
  if (bx < 64)      { in = Wq; out = WqT; C = 2048; cbl = bx; }
  else if (bx < 80) { in = Wk; out = WkT; C = 512;  cbl = bx - 64; }
  else if (bx < 96) { in = Wv; out = WvT; C = 512;  cbl = bx - 80; }
  else              { in = Wo; out = WoT; C = 2048; cbl = bx - 96; }
  const int R = 2048;
  int c0 = cbl * 32, r0 = blockIdx.y * 32;
  #pragma unroll
  for (int k = 0; k < 32; k += 8)
    tile[ty + k][tx] = in[(size_t)(r0 + ty + k) * C + c0 + tx];
  __syncthreads();
  #pragma unroll
  for (int k = 0; k < 32; k += 8)
    out[(size_t)(c0 + ty + k) * R + r0 + tx] = (bf16_t)tile[tx][ty + k];
}

// XCD chunking (nb divisible by 8) + 4x4 supertile serpentine mapping
__device__ __forceinline__ int xcd_swz(int bid, int nb) {
  const int q = nb >> 3;
  return (bid & 7) * q + (bid >> 3);
}
__device__ __forceinline__ void st_map(int lin, int nstc, int& rb, int& cb) {
  const int stid = lin >> 4, w = lin & 15;
  const int sr = stid / nstc, t = stid - sr * nstc;
  const int sc = (sr & 1) ? (nstc - 1 - t) : t;
  rb = sr * 4 + (w >> 2);
  cb = sc * 4 + (w & 3);
}

// ---------------- GEMM (r17/r15 form): BK=64, XCD+supertile swizzle, fused epilogues ----
// MODE 0 (QKV, 768 blocks, 64x128): A raw f32 reg-staged+cast, 2-deep reg prefetch;
//   B via global_load_lds. cb<16 Q->RoPE qh; cb<20 K->RoPE kgr; else V->vT vtg.
// MODE 1 (O-proj, 1024 blocks, 64x64): A,B via global_load_lds; f32 out + bias.
template<int MODE>
__global__ __launch_bounds__(256) void gemm_glds_k(
    const void* __restrict__ Aq, const void* __restrict__ Ak, const void* __restrict__ Av,
    const bf16_t* __restrict__ Bq, const bf16_t* __restrict__ Bk, const bf16_t* __restrict__ Bv,
    const int K, const float* __restrict__ cs, const float* __restrict__ sn,
    bf16_t* __restrict__ oq, bf16_t* __restrict__ okg, bf16_t* __restrict__ ovt,
    float* __restrict__ ofp, const float* __restrict__ bias, const int S) {
  constexpr int BN   = (MODE == 0) ? 128 : 64;   // N-tile
  constexpr int NI   = BN / 32;                  // N frags per wave
  constexpr int BU   = BN / 32;                  // B staging units per wave
  constexpr int NB   = (MODE == 0) ? 768 : 1024;
  constexpr int NSTC = (MODE == 0) ? 6 : 8;
  __shared__ bf16_t a_lds[64 * 64];
  __shared__ bf16_t b_lds[BN * 64];
  const int tid = threadIdx.x, wid = tid >> 6, lane = tid & 63;
  const int fr = lane & 15, kg = lane >> 4;

  const int lin = xcd_swz(blockIdx.x, NB);
  int rb, cb; st_map(lin, NSTC, rb, cb);
  const void* Ap; const bf16_t* Bp; int emode, col0;
  if (MODE == 1)    { Ap = Aq; Bp = Bq; emode = 3; col0 = cb * BN; }
  else if (cb < 16) { Ap = Aq; Bp = Bq; emode = 0; col0 = cb * 128; }
  else if (cb < 20) { Ap = Ak; Bp = Bk; emode = 1; col0 = (cb - 16) * 128; }
  else              { Ap = Av; Bp = Bv; emode = 2; col0 = (cb - 20) * 128; }
  const int row0 = rb * 64;
  const int wr = (wid >> 1) * 32, wc = (wid & 1) * (BN / 2);

  f32x4 acc[2][NI];
  #pragma unroll
  for (int i = 0; i < 2; ++i)
    #pragma unroll
    for (int j = 0; j < NI; ++j)
      acc[i][j] = (f32x4){0.f, 0.f, 0.f, 0.f};

  // B staging: lane l -> row sub*8+(l>>3), LDS chunk l&7, source chunk (l&7)^(row&7).
  const int rloc = lane >> 3;
  const int schunk = ((lane & 7) ^ rloc) * 8;
  const bf16_t* gB[BU];
  bf16_t* lB[BU];
  #pragma unroll
  for (int u = 0; u < BU; ++u) {
    gB[u] = Bp + (size_t)(col0 + (wid * BU + u) * 8 + rloc) * K + schunk;
    lB[u] = &b_lds[(wid * BU + u) * 512];
  }

#define MFMA_STEP                                                              \
  do {                                                                         \
    _Pragma("unroll")                                                          \
    for (int ks = 0; ks < 2; ++ks) {                                           \
      bf16x8 af[2], bfr[NI];                                                   \
      _Pragma("unroll")                                                        \
      for (int mi = 0; mi < 2; ++mi) {                                         \
        const int r = wr + mi * 16 + fr;                                       \
        af[mi] = *(const bf16x8*)&a_lds[r * 64 + (((ks * 4 + kg) ^ (fr & 7)) * 8)]; \
      }                                                                        \
      _Pragma("unroll")                                                        \
      for (int ni = 0; ni < NI; ++ni) {                                        \
        const int r = wc + ni * 16 + fr;                                       \
        bfr[ni] = *(const bf16x8*)&b_lds[r * 64 + (((ks * 4 + kg) ^ (fr & 7)) * 8)]; \
      }                                                                        \
      _Pragma("unroll")                                                        \
      for (int mi = 0; mi < 2; ++mi)                                           \
        _Pragma("unroll")                                                      \
        for (int ni = 0; ni < NI; ++ni)                                        \
          acc[mi][ni] = __builtin_amdgcn_mfma_f32_16x16x32_bf16(af[mi], bfr[ni], acc[mi][ni], 0, 0, 0); \
    }                                                                          \
  } while (0)

  if (MODE == 0) {
    const float* Afp = (const float*)Ap;
    const int arow = wid * 16 + (lane >> 2);
    const int acol = (lane & 3) * 16;
    const int c0w = (lane & 3) * 2;
    const int wofs0 = arow * 64 + ((c0w ^ (arow & 7)) * 8);
    const int wofs1 = arow * 64 + (((c0w + 1) ^ (arow & 7)) * 8);
    const float* abase = &Afp[(size_t)(row0 + arow) * K + acol];
    f32x4 pA0, pA1, pA2, pA3, pB0, pB1, pB2, pB3;
    pA0 = *(const f32x4*)(abase);      pA1 = *(const f32x4*)(abase + 4);
    pA2 = *(const f32x4*)(abase + 8);  pA3 = *(const f32x4*)(abase + 12);
    pB0 = *(const f32x4*)(abase + 64); pB1 = *(const f32x4*)(abase + 68);
    pB2 = *(const f32x4*)(abase + 72); pB3 = *(const f32x4*)(abase + 76);

#define A_WRITE(r0_, r1_, r2_, r3_)                                            \
    do {                                                                       \
      bf16x8 w0, w1;                                                           \
      w0[0]=(bf16_t)r0_[0]; w0[1]=(bf16_t)r0_[1]; w0[2]=(bf16_t)r0_[2]; w0[3]=(bf16_t)r0_[3]; \
      w0[4]=(bf16_t)r1_[0]; w0[5]=(bf16_t)r1_[1]; w0[6]=(bf16_t)r1_[2]; w0[7]=(bf16_t)r1_[3]; \
      w1[0]=(bf16_t)r2_[0]; w1[1]=(bf16_t)r2_[1]; w1[2]=(bf16_t)r2_[2]; w1[3]=(bf16_t)r2_[3]; \
      w1[4]=(bf16_t)r3_[0]; w1[5]=(bf16_t)r3_[1]; w1[6]=(bf16_t)r3_[2]; w1[7]=(bf16_t)r3_[3]; \
      *(bf16x8*)&a_lds[wofs0] = w0;                                            \
      *(bf16x8*)&a_lds[wofs1] = w1;                                            \
    } while (0)

    for (int kt = 0; kt < K; kt += 128) {
      // ---- phase 1: tile kt (regs pA*) ----
      __syncthreads();
      A_WRITE(pA0, pA1, pA2, pA3);
      #pragma unroll
      for (int u = 0; u < BU; ++u) GLDS(gB[u] + kt, lB[u]);
      __syncthreads();
      if (kt + 128 < K) {
        const float* p = abase + kt + 128;
        pA0 = *(const f32x4*)(p);     pA1 = *(const f32x4*)(p + 4);
        pA2 = *(const f32x4*)(p + 8); pA3 = *(const f32x4*)(p + 12);
      }
      MFMA_STEP;
      // ---- phase 2: tile kt+64 (regs pB*) ----
      __syncthreads();
      A_WRITE(pB0, pB1, pB2, pB3);
      #pragma unroll
      for (int u = 0; u < BU; ++u) GLDS(gB[u] + kt + 64, lB[u]);
      __syncthreads();
      if (kt + 192 < K) {
        const float* p = abase + kt + 192;
        pB0 = *(const f32x4*)(p);     pB1 = *(const f32x4*)(p + 4);
        pB2 = *(const f32x4*)(p + 8); pB3 = *(const f32x4*)(p + 12);
      }
      MFMA_STEP;
    }
#undef A_WRITE
  } else {
    const bf16_t* gA0 = (const bf16_t*)Ap + (size_t)(row0 + (wid * 2 + 0) * 8 + rloc) * K + schunk;
    const bf16_t* gA1 = (const bf16_t*)Ap + (size_t)(row0 + (wid * 2 + 1) * 8 + rloc) * K + schunk;
    bf16_t* lA0 = &a_lds[(wid * 2 + 0) * 512];
    bf16_t* lA1 = &a_lds[(wid * 2 + 1) * 512];
    for (int kt = 0; kt < K; kt += 64) {
      __syncthreads();
      GLDS(gA0 + kt, lA0);
      GLDS(gA1 + kt, lA1);
      #pragma unroll
      for (int u = 0; u < BU; ++u) GLDS(gB[u] + kt, lB[u]);
      __syncthreads();
      MFMA_STEP;
    }
  }
#undef MFMA_STEP

  #pragma unroll
  for (int mi = 0; mi < 2; ++mi) {
    #pragma unroll
    for (int ni = 0; ni < NI; ++ni) {
      #pragma unroll
      for (int r = 0; r < 4; ++r) {
        const int grow = row0 + wr + mi * 16 + kg * 4 + r;  // C row = 4*(lane>>4)+reg
        const int gcol = col0 + wc + ni * 16 + fr;          // C col = lane&15
        float v = acc[mi][ni][r];
        if (emode == 3) {
          ofp[(size_t)grow * 2048 + gcol] = v + bias[gcol];
        } else if (emode == 2) {
          const int gi = gcol >> 6, d = gcol & 63;
          ovt[((size_t)gi * 64 + d) * S + grow] = (bf16_t)v;
        } else {
          const float pv = __shfl_xor(v, 1);  // RoPE partner (d^1), same row
          const int d = gcol & 63, p = d >> 1, hh = gcol >> 6;
          const float c = cs[grow * 32 + p], s = sn[grow * 32 + p];
          float o = (d & 1) ? fmaf(pv, s, v * c) : fmaf(-pv, s, v * c);
          if (emode == 0) {
            o *= 0.125f * LOG2E;  // fold 1/sqrt(64) and log2(e) into q
            oq[((size_t)hh * S + grow) * 64 + d] = (bf16_t)o;
          } else {
            okg[((size_t)hh * S + grow) * 64 + d] = (bf16_t)o;
          }
        }
      }
    }
  }
}

// XOR-swizzled LDS index (T2): row stride 64 bf16 (128B), 16B chunk c^(row&7).
__device__ __forceinline__ int swz8(int r, int c) { return r * 64 + (((c) ^ (r & 7)) << 3); }

// ---------------- flash attention v4 (r11 core, no setprio): swizzle + defer-max ----
__global__ __launch_bounds__(256) void attn_k(
    const bf16_t* __restrict__ qh,   // [32][S][64], pre-scaled by 0.125*log2e
    const bf16_t* __restrict__ kgr,  // [8][S][64]
    const bf16_t* __restrict__ vtg,  // [8][64][S]
    const int* __restrict__ amask,   // [S]
    bf16_t* __restrict__ ao,         // [S][2048]
    const int S) {
  __shared__ bf16_t k_lds[64 * 64];
  __shared__ bf16_t vt_lds[64 * 64];
  __shared__ bf16_t p_lds[4][16 * 64];
  const int tid = threadIdx.x, wid = tid >> 6, lane = tid & 63;
  const int fr = lane & 15, kgp = lane >> 4;
  const int h = blockIdx.x, g = h >> 2;
  const int qb = 31 - blockIdx.y;      // LPT: heavy blocks first in dispatch order
  const int q0 = qb * 64 + wid * 16;
  const int qg = q0 + fr;

  const bf16_t* qbase = qh + ((size_t)h * S + q0 + fr) * 64;
  const bf16x8 qf0 = *(const bf16x8*)&qbase[kgp * 8];
  const bf16x8 qf1 = *(const bf16x8*)&qbase[32 + kgp * 8];

  f32x4 oacc[4];
  #pragma unroll
  for (int t = 0; t < 4; ++t) oacc[t] = (f32x4){0.f, 0.f, 0.f, 0.f};
  float m_ = -1e30f, l_ = 0.f;

  const int srow = tid >> 2, sc4 = tid & 3;
  const bf16_t* kbase = kgr + (size_t)g * S * 64;
  const bf16_t* vbase = vtg + (size_t)g * 64 * S;
  const int cmax = qb + 1;

  bf16x8 nk0 = *(const bf16x8*)&kbase[(size_t)srow * 64 + sc4 * 8];
  bf16x8 nk1 = *(const bf16x8*)&kbase[(size_t)srow * 64 + 32 + sc4 * 8];
  bf16x8 nv0 = *(const bf16x8*)&vbase[(size_t)srow * S + sc4 * 8];
  bf16x8 nv1 = *(const bf16x8*)&vbase[(size_t)srow * S + 32 + sc4 * 8];
  int mvc = amask[lane];
  *(bf16x8*)&k_lds[swz8(srow, sc4)]      = nk0;
  *(bf16x8*)&k_lds[swz8(srow, 4 + sc4)]  = nk1;
  *(bf16x8*)&vt_lds[swz8(srow, sc4)]     = nv0;
  *(bf16x8*)&vt_lds[swz8(srow, 4 + sc4)] = nv1;
  __syncthreads();

  for (int c = 0; c < cmax; ++c) {
    const int kc0 = c * 64;
    const unsigned long long pm = __ballot(mvc == 0);
    const bool more = (c + 1 < cmax);
    if (more) {  // issue-early prefetch (written after compute)
      const int kc1 = kc0 + 64;
      nk0 = *(const bf16x8*)&kbase[(size_t)(kc1 + srow) * 64 + sc4 * 8];
      nk1 = *(const bf16x8*)&kbase[(size_t)(kc1 + srow) * 64 + 32 + sc4 * 8];
      nv0 = *(const bf16x8*)&vbase[(size_t)srow * S + kc1 + sc4 * 8];
      nv1 = *(const bf16x8*)&vbase[(size_t)srow * S + kc1 + 32 + sc4 * 8];
      mvc = amask[kc1 + lane];
    }

    f32x4 sc[4];
    #pragma unroll
    for (int a = 0; a < 4; ++a) {
      const bf16x8 ka0 = *(const bf16x8*)&k_lds[swz8(a * 16 + fr, kgp)];
      const bf16x8 ka1 = *(const bf16x8*)&k_lds[swz8(a * 16 + fr, 4 + kgp)];
      f32x4 z = (f32x4){0.f, 0.f, 0.f, 0.f};
      z = __builtin_amdgcn_mfma_f32_16x16x32_bf16(ka0, qf0, z, 0, 0, 0);
      z = __builtin_amdgcn_mfma_f32_16x16x32_bf16(ka1, qf1, z, 0, 0, 0);
      sc[a] = z;
    }

    if (c == qb) {  // causal: only the diagonal chunk can cross
      #pragma unroll
      for (int a = 0; a < 4; ++a)
        #pragma unroll
        for (int r = 0; r < 4; ++r) {
          const int kl = a * 16 + 4 * kgp + r;
          if (kc0 + kl > qg) sc[a][r] = -1e30f;
        }
    }
    if (pm) {       // pad mask: all-ones input -> skipped (wave-uniform)
      #pragma unroll
      for (int a = 0; a < 4; ++a)
        #pragma unroll
        for (int r = 0; r < 4; ++r) {
          const int kl = a * 16 + 4 * kgp + r;
          if ((pm >> kl) & 1) sc[a][r] = -1e30f;
        }
    }

    float t0 = fmaxf(fmaxf(sc[0][0], sc[0][1]), fmaxf(sc[0][2], sc[0][3]));
    float t1 = fmaxf(fmaxf(sc[1][0], sc[1][1]), fmaxf(sc[1][2], sc[1][3]));
    float t2 = fmaxf(fmaxf(sc[2][0], sc[2][1]), fmaxf(sc[2][2], sc[2][3]));
    float t3 = fmaxf(fmaxf(sc[3][0], sc[3][1]), fmaxf(sc[3][2], sc[3][3]));
    float smax = fmaxf(fmaxf(t0, t1), fmaxf(t2, t3));
    smax = fmaxf(smax, __shfl_xor(smax, 16));
    smax = fmaxf(smax, __shfl_xor(smax, 32));

    // defer-max (T13): skip rescale while the running max grows < 8 (log2 units)
    const bool rescale = !__all(smax <= m_ + 8.0f);
    if (rescale) {
      const float mn = fmaxf(m_, smax);
      const float al = exp2f(m_ - mn);
      m_ = mn;
      #pragma unroll
      for (int t = 0; t < 4; ++t)
        #pragma unroll
        for (int r = 0; r < 4; ++r) oacc[t][r] *= al;
      l_ *= al;
    }

    float ps = 0.f;
    #pragma unroll
    for (int a = 0; a < 4; ++a)
      #pragma unroll
      for (int r = 0; r < 4; ++r) {
        const float p = exp2f(sc[a][r] - m_);
        sc[a][r] = p;
        ps += p;
      }
    ps += __shfl_xor(ps, 16);
    ps += __shfl_xor(ps, 32);
    l_ += ps;

    #pragma unroll
    for (int a = 0; a < 4; ++a) {
      bf16x4 w;
      w[0] = (bf16_t)sc[a][0];
      w[1] = (bf16_t)sc[a][1];
      w[2] = (bf16_t)sc[a][2];
      w[3] = (bf16_t)sc[a][3];
      const int off = a * 16 + 4 * kgp;
      *(bf16x4*)&p_lds[wid][fr * 64 + (((off >> 3) ^ (fr & 7)) << 3) + (off & 7)] = w;
    }
    const bf16x8 pa0 = *(const bf16x8*)&p_lds[wid][swz8(fr, kgp)];
    const bf16x8 pa1 = *(const bf16x8*)&p_lds[wid][swz8(fr, 4 + kgp)];

    #pragma unroll
    for (int t = 0; t < 4; ++t) {
      const bf16x8 vb0 = *(const bf16x8*)&vt_lds[swz8(t * 16 + fr, kgp)];
      const bf16x8 vb1 = *(const bf16x8*)&vt_lds[swz8(t * 16 + fr, 4 + kgp)];
      oacc[t] = __builtin_amdgcn_mfma_f32_16x16x32_bf16(vb0, pa0, oacc[t], 0, 0, 0);
      oacc[t] = __builtin_amdgcn_mfma_f32_16x16x32_bf16(vb1, pa1, oacc[t], 0, 0, 0);
    }

    if (more) {
      __syncthreads();
      *(bf16x8*)&k_lds[swz8(srow, sc4)]      = nk0;
      *(bf16x8*)&k_lds[swz8(srow, 4 + sc4)]  = nk1;
      *(bf16x8*)&vt_lds[swz8(srow, sc4)]     = nv0;
      *(bf16x8*)&vt_lds[swz8(srow, 4 + sc4)] = nv1;
      __syncthreads();
    }
  }

  const float inv = 1.0f / l_;
  #pragma unroll
  for (int t = 0; t < 4; ++t) {
    bf16x4 o4;
    #pragma unroll
    for (int r = 0; r < 4; ++r) o4[r] = (bf16_t)(oacc[t][r] * inv);
    *(bf16x4*)&ao[(size_t)(q0 + fr) * 2048 + h * 64 + t * 16 + 4 * kgp] = o4;
  }
}

// ---------------- launcher ----------------
extern "C" void kernel_launch(void* const* d_in, const int* in_sizes, int n_in,
                              void* d_out, int out_size, void* d_ws, size_t ws_size,
                              hipStream_t stream) {
  const float* Q  = (const float*)d_in[0];
  const float* K  = (const float*)d_in[1];
  const float* V  = (const float*)d_in[2];
  const int*   am = (const int*)d_in[3];
  const float* Wq = (const float*)d_in[4];
  const float* Wk = (const float*)d_in[5];
  const float* Wv = (const float*)d_in[6];
  const float* Wo = (const float*)d_in[7];
  const float* bo = (const float*)d_in[8];
  float* out = (float*)d_out;

  const int S = 2048, D = 2048;
  char* w = (char*)d_ws;
  const size_t MB = 1u << 20;
  bf16_t* WqT = (bf16_t*)(w + 0 * MB);   // [D][D]
  bf16_t* WoT = (bf16_t*)(w + 8 * MB);   // [D][D]
  bf16_t* WkT = (bf16_t*)(w + 16 * MB);  // [KV][D]
  bf16_t* WvT = (bf16_t*)(w + 18 * MB);
  bf16_t* qh  = (bf16_t*)(w + 20 * MB);  // [32][S][64]
  bf16_t* kgr = (bf16_t*)(w + 28 * MB);  // [8][S][64]
  bf16_t* vtg = (bf16_t*)(w + 30 * MB);  // [8][64][S]
  bf16_t* ao  = (bf16_t*)(w + 32 * MB);  // [S][D]
  float*  cs  = (float*)(w + 40 * MB);   // [S][32]
  float*  sn  = (float*)(w + 40 * MB + 256 * 1024);

  // fused prep: weight transposes + RoPE table
  prep_k<<<dim3(164, 64), dim3(32, 8), 0, stream>>>(Wq, Wk, Wv, Wo, WqT, WkT, WvT, WoT, cs, sn);

  // fused Q+K+V projections from f32 inputs (2-deep A reg prefetch)
  gemm_glds_k<0><<<768, 256, 0, stream>>>(Q, K, V, WqT, WkT, WvT, D,
                                          cs, sn, qh, kgr, vtg, nullptr, nullptr, S);

  // attention (r11 kernel; setprio removed — measured null-to-negative on this structure)
  attn_k<<<dim3(32, 32), 256, 0, stream>>>(qh, kgr, vtg, am, ao, S);

  // O-proj: 1024 blocks (64x64 tiles), global_load_lds staging
  gemm_glds_k<1><<<1024, 256, 0, stream>>>(ao, nullptr, nullptr, WoT, nullptr, nullptr,
                                           D, nullptr, nullptr, nullptr, nullptr, nullptr,
                                           out, bo, S);
}